// Round 5
// baseline (798.248 us; speedup 1.0000x reference)
//
#include <hip/hip_runtime.h>
#include <hip/hip_bf16.h>

#define N_NODES 50000
#define N_EDGES 800000
#define D 128
#define N_PAD 50176          // 392 * 128
#define NBUCKET 392          // dst >> 7
#define BKT_PAD 400
#define PCHUNK 4096          // edges per partition block
#define NPBLK ((N_EDGES + PCHUNK - 1) / PCHUNK)  // 196

typedef __attribute__((ext_vector_type(8))) short bf16x8;
typedef __attribute__((ext_vector_type(4))) float f32x4;

__device__ inline unsigned short f2bf(float f) {
  unsigned u = __float_as_uint(f);
  unsigned r = (u + 0x7FFFu + ((u >> 16) & 1u)) >> 16;
  return (unsigned short)r;
}

// ---------------- prep: h f32 -> packed bf16 table, + per-node histogram ------
__global__ __launch_bounds__(256) void prep_kernel(const float* __restrict__ h,
                                                   unsigned* __restrict__ h_bf,
                                                   const int* __restrict__ dst,
                                                   int* __restrict__ count) {
  int i = blockIdx.x * blockDim.x + threadIdx.x;
  if (i < N_NODES * D / 4) {
    float4 f = ((const float4*)h)[i];
    unsigned lo = ((unsigned)f2bf(f.y) << 16) | f2bf(f.x);
    unsigned hi = ((unsigned)f2bf(f.w) << 16) | f2bf(f.z);
    ((uint2*)h_bf)[i] = make_uint2(lo, hi);
  }
  if (i < N_EDGES) atomicAdd(&count[dst[i]], 1);
}

// ---------------- bucket sums from node histogram (1 wave per bucket) --------
__global__ __launch_bounds__(256) void bsum_kernel(const int* __restrict__ count,
                                                   int* __restrict__ bucket_count) {
  int b = blockIdx.x * 4 + (threadIdx.x >> 6);
  int lane = threadIdx.x & 63;
  if (b >= NBUCKET) return;
  int s = count[b * 128 + lane] + count[b * 128 + 64 + lane];
#pragma unroll
  for (int off = 32; off >= 1; off >>= 1) s += __shfl_xor(s, off, 64);
  if (lane == 0) bucket_count[b] = s;
}

// wave 0: exclusive scan of 392 bucket counts -> bstart & gcursor;
// all 1024 threads: convert W to bf16.
__global__ __launch_bounds__(1024) void scan_convw(const int* __restrict__ bucket_count,
                                                   int* __restrict__ bstart,
                                                   int* __restrict__ gcursor,
                                                   const float4* __restrict__ Wm4,
                                                   ushort4* __restrict__ W4) {
  int t = threadIdx.x;
  if (t < 64) {
    int carry = 0;
    for (int base = 0; base < NBUCKET; base += 64) {
      int i = base + t;
      int v = (i < NBUCKET) ? bucket_count[i] : 0;
      int incl = v;
#pragma unroll
      for (int off = 1; off < 64; off <<= 1) {
        int y = __shfl_up(incl, off, 64);
        if (t >= off) incl += y;
      }
      int excl = incl - v + carry;
      if (i < NBUCKET) { bstart[i] = excl; gcursor[i] = excl; }
      carry += __shfl(incl, 63, 64);
    }
    if (t == 0) bstart[NBUCKET] = carry;
  }
  for (int i = t; i < D * D / 4; i += 1024) {
    float4 f = Wm4[i];
    ushort4 o;
    o.x = f2bf(f.x); o.y = f2bf(f.y); o.z = f2bf(f.z); o.w = f2bf(f.w);
    W4[i] = o;
  }
}

// ---------------- LDS-staged radix partition by dst bucket -------------------
// record: [dst:32 | src:16 | w_q16:16]
__global__ __launch_bounds__(256) void partition_kernel(const int* __restrict__ src,
                                                        const int* __restrict__ dst,
                                                        const float* __restrict__ w,
                                                        int* __restrict__ gcursor,
                                                        unsigned long long* __restrict__ recs) {
  __shared__ int lhist[NBUCKET];
  __shared__ int lstart[NBUCKET];
  __shared__ int lcur[NBUCKET];
  __shared__ int gbase[NBUCKET];
  __shared__ unsigned long long staged[PCHUNK];
  int t = threadIdx.x;
  int e0 = blockIdx.x * PCHUNK;
  int nch = N_EDGES - e0; if (nch > PCHUNK) nch = PCHUNK;

  for (int i = t; i < NBUCKET; i += 256) lhist[i] = 0;
  __syncthreads();

  unsigned long long rec[PCHUNK / 256];
  int rbkt[PCHUNK / 256];
#pragma unroll
  for (int k = 0; k < PCHUNK / 256; ++k) {
    int idx = t + k * 256;
    if (idx < nch) {
      int e = e0 + idx;
      int s = src[e];
      int d_ = dst[e];
      unsigned q = (unsigned)__float2uint_rn(w[e] * 65535.f);
      rbkt[k] = d_ >> 7;
      rec[k] = ((unsigned long long)(unsigned)d_ << 32) | ((unsigned)s << 16) | q;
      atomicAdd(&lhist[rbkt[k]], 1);
    } else {
      rbkt[k] = -1;
      rec[k] = 0;
    }
  }
  __syncthreads();

  if (t < 64) {  // exclusive scan lhist -> lstart
    int carry = 0;
    for (int base = 0; base < NBUCKET; base += 64) {
      int i = base + t;
      int v = (i < NBUCKET) ? lhist[i] : 0;
      int incl = v;
#pragma unroll
      for (int off = 1; off < 64; off <<= 1) {
        int y = __shfl_up(incl, off, 64);
        if (t >= off) incl += y;
      }
      if (i < NBUCKET) lstart[i] = incl - v + carry;
      carry += __shfl(incl, 63, 64);
    }
  }
  __syncthreads();

  for (int i = t; i < NBUCKET; i += 256) {
    gbase[i] = atomicAdd(&gcursor[i], lhist[i]);
    lcur[i] = lstart[i];
  }
  __syncthreads();

#pragma unroll
  for (int k = 0; k < PCHUNK / 256; ++k) {
    if (rbkt[k] >= 0) {
      int lp = atomicAdd(&lcur[rbkt[k]], 1);
      staged[lp] = rec[k];
    }
  }
  __syncthreads();

  for (int i = t; i < nch; i += 256) {
    unsigned long long r = staged[i];
    int bkt = (int)(r >> 32) >> 7;
    recs[gbase[bkt] + (i - lstart[bkt])] = r;
  }
}

// ---------------- aggregate: LDS f32 accumulate per bucket, mean+tanh --------
// block = bucket of 128 nodes; acc planes [node][64] (bank = lane%32, 2-way free).
__global__ __launch_bounds__(256) void aggregate_kernel(const unsigned* __restrict__ h_bf,
                                                        const unsigned long long* __restrict__ recs,
                                                        const int* __restrict__ bstart,
                                                        const int* __restrict__ count,
                                                        float* __restrict__ hact) {
  __shared__ float acc0[128 * 64];
  __shared__ float acc1[128 * 64];
  int t = threadIdx.x;
  int b = blockIdx.x;
  int lane = t & 63, wid = t >> 6;
  for (int i = t; i < 128 * 64; i += 256) { acc0[i] = 0.f; acc1[i] = 0.f; }
  __syncthreads();

  int beg = bstart[b], end = bstart[b + 1];
  const float WS = 1.0f / 65535.0f;
  int r = beg + wid;
  for (; r + 12 < end; r += 16) {
    unsigned long long p0 = recs[r], p1 = recs[r + 4], p2 = recs[r + 8], p3 = recs[r + 12];
    int s0 = (int)(p0 >> 16) & 0xFFFF, s1 = (int)(p1 >> 16) & 0xFFFF;
    int s2 = (int)(p2 >> 16) & 0xFFFF, s3 = (int)(p3 >> 16) & 0xFFFF;
    unsigned v0 = h_bf[s0 * 64 + lane];
    unsigned v1 = h_bf[s1 * 64 + lane];
    unsigned v2 = h_bf[s2 * 64 + lane];
    unsigned v3 = h_bf[s3 * 64 + lane];
    float w0 = (float)((unsigned)p0 & 0xFFFFu) * WS;
    float w1 = (float)((unsigned)p1 & 0xFFFFu) * WS;
    float w2 = (float)((unsigned)p2 & 0xFFFFu) * WS;
    float w3 = (float)((unsigned)p3 & 0xFFFFu) * WS;
    int n0 = ((int)(p0 >> 32) & 127) * 64 + lane;
    int n1 = ((int)(p1 >> 32) & 127) * 64 + lane;
    int n2 = ((int)(p2 >> 32) & 127) * 64 + lane;
    int n3 = ((int)(p3 >> 32) & 127) * 64 + lane;
    atomicAdd(&acc0[n0], __uint_as_float(v0 << 16) * w0);
    atomicAdd(&acc1[n0], __uint_as_float(v0 & 0xFFFF0000u) * w0);
    atomicAdd(&acc0[n1], __uint_as_float(v1 << 16) * w1);
    atomicAdd(&acc1[n1], __uint_as_float(v1 & 0xFFFF0000u) * w1);
    atomicAdd(&acc0[n2], __uint_as_float(v2 << 16) * w2);
    atomicAdd(&acc1[n2], __uint_as_float(v2 & 0xFFFF0000u) * w2);
    atomicAdd(&acc0[n3], __uint_as_float(v3 << 16) * w3);
    atomicAdd(&acc1[n3], __uint_as_float(v3 & 0xFFFF0000u) * w3);
  }
  for (; r < end; r += 4) {
    unsigned long long p = recs[r];
    int s = (int)(p >> 16) & 0xFFFF;
    unsigned v = h_bf[s * 64 + lane];
    float we = (float)((unsigned)p & 0xFFFFu) * WS;
    int n = ((int)(p >> 32) & 127) * 64 + lane;
    atomicAdd(&acc0[n], __uint_as_float(v << 16) * we);
    atomicAdd(&acc1[n], __uint_as_float(v & 0xFFFF0000u) * we);
  }
  __syncthreads();

  for (int i = t; i < 128 * 64; i += 256) {
    int nl = i >> 6, l = i & 63;
    int gn = b * 128 + nl;
    if (gn < N_NODES) {
      int deg = count[gn];
      float inv = (deg > 0) ? 1.f / (float)deg : 0.f;
      float2 o;
      o.x = tanhf(acc0[i] * inv);
      o.y = tanhf(acc1[i] * inv);
      ((float2*)hact)[gn * 64 + l] = o;
    }
  }
}

// ---------------- out = tanh-act @ W^T + b via MFMA bf16, in place on d_out ----
__global__ __launch_bounds__(256) void gemm_kernel(const float* __restrict__ hact,
                                                   const unsigned short* __restrict__ W_bf,
                                                   const float* __restrict__ bias,
                                                   float* __restrict__ out) {
  int lane = threadIdx.x & 63;
  int wid  = threadIdx.x >> 6;
  int n_base = blockIdx.x * 64 + wid * 16;
  int m  = lane & 15;
  int kg = lane >> 4;
  int n = n_base + m;
  int n_c = (n < N_NODES) ? n : (N_NODES - 1);

  bf16x8 afrag[4];
  const float* arow = hact + (size_t)n_c * D;
#pragma unroll
  for (int kc = 0; kc < 4; ++kc) {
    int k0 = kc * 32 + kg * 8;
    float4 lo = *(const float4*)(arow + k0);
    float4 hi = *(const float4*)(arow + k0 + 4);
    bf16x8 a;
    a[0] = (short)f2bf(lo.x); a[1] = (short)f2bf(lo.y);
    a[2] = (short)f2bf(lo.z); a[3] = (short)f2bf(lo.w);
    a[4] = (short)f2bf(hi.x); a[5] = (short)f2bf(hi.y);
    a[6] = (short)f2bf(hi.z); a[7] = (short)f2bf(hi.w);
    afrag[kc] = a;
  }

#pragma unroll
  for (int jt = 0; jt < 8; ++jt) {
    int j = jt * 16 + m;
    const unsigned short* wrow = W_bf + j * D;
    f32x4 acc = {0.f, 0.f, 0.f, 0.f};
#pragma unroll
    for (int kc = 0; kc < 4; ++kc) {
      bf16x8 bb = *(const bf16x8*)(wrow + kc * 32 + kg * 8);
      acc = __builtin_amdgcn_mfma_f32_16x16x32_bf16(afrag[kc], bb, acc, 0, 0, 0);
    }
    float bj = bias[j];
#pragma unroll
    for (int rr = 0; rr < 4; ++rr) {
      int nn = n_base + kg * 4 + rr;
      if (nn < N_NODES) out[(size_t)nn * D + j] = acc[rr] + bj;
    }
  }
}

extern "C" void kernel_launch(void* const* d_in, const int* in_sizes, int n_in,
                              void* d_out, int out_size, void* d_ws, size_t ws_size,
                              hipStream_t stream) {
  const float* h    = (const float*)d_in[0];
  const float* w    = (const float*)d_in[1];
  const int*   src  = (const int*)d_in[2];
  const int*   dst  = (const int*)d_in[3];
  const float* Wm   = (const float*)d_in[4];
  const float* bias = (const float*)d_in[5];
  float* out = (float*)d_out;

  // ws layout:
  //   count:        [0,        200704)   (N_PAD ints)
  //   bucket_count: [200704,   202304)   (BKT_PAD ints)
  //   bstart:       [202304,   203904)   (BKT_PAD ints; bstart[392] valid)
  //   gcursor:      [203904,   205504)
  //   W_bf:         [205504,   238272)
  //   h_bf:         [238272,   13038272) (12.8 MB)
  //   recs:         [13038272, 19438272) (6.4 MB, 8B records)
  char* ws = (char*)d_ws;
  int*                count        = (int*)(ws);
  int*                bucket_count = (int*)(ws + 200704);
  int*                bstart       = (int*)(ws + 202304);
  int*                gcursor      = (int*)(ws + 203904);
  unsigned short*     W_bf         = (unsigned short*)(ws + 205504);
  unsigned*           h_bf         = (unsigned*)(ws + 238272);
  unsigned long long* recs         = (unsigned long long*)(ws + 13038272);

  hipMemsetAsync(count, 0, (N_PAD + BKT_PAD) * sizeof(int), stream);  // count + bucket_count
  prep_kernel<<<(N_NODES * D / 4 + 255) / 256, 256, 0, stream>>>(h, h_bf, dst, count);
  bsum_kernel<<<(NBUCKET + 3) / 4, 256, 0, stream>>>(count, bucket_count);
  scan_convw<<<1, 1024, 0, stream>>>(bucket_count, bstart, gcursor, (const float4*)Wm, (ushort4*)W_bf);
  partition_kernel<<<NPBLK, 256, 0, stream>>>(src, dst, w, gcursor, recs);
  aggregate_kernel<<<NBUCKET, 256, 0, stream>>>(h_bf, recs, bstart, count, out);
  gemm_kernel<<<(N_NODES + 63) / 64, 256, 0, stream>>>(out, W_bf, bias, out);
}

// Round 6
// 139.034 us; speedup vs baseline: 5.7414x; 5.7414x over previous
//
#include <hip/hip_runtime.h>
#include <hip/hip_bf16.h>

#define N_NODES 50000
#define N_EDGES 800000
#define D 128
#define N_PAD 50176          // 392 * 128
#define NBUCKET 392          // dst >> 7 (max used: 390)
#define SCAN_BLOCKS 49
#define PCHUNK 4096
#define NPBLK ((N_EDGES + PCHUNK - 1) / PCHUNK)  // 196

typedef __attribute__((ext_vector_type(8))) short bf16x8;
typedef __attribute__((ext_vector_type(4))) float f32x4;

__device__ inline unsigned short f2bf(float f) {
  unsigned u = __float_as_uint(f);
  unsigned r = (u + 0x7FFFu + ((u >> 16) & 1u)) >> 16;
  return (unsigned short)r;
}

// ---------------- prep: h f32 -> packed bf16 table, + per-node histogram ------
__global__ __launch_bounds__(256) void prep_kernel(const float* __restrict__ h,
                                                   unsigned* __restrict__ h_bf,
                                                   const int* __restrict__ dst,
                                                   int* __restrict__ count) {
  int i = blockIdx.x * blockDim.x + threadIdx.x;
  if (i < N_NODES * D / 4) {
    float4 f = ((const float4*)h)[i];
    unsigned lo = ((unsigned)f2bf(f.y) << 16) | f2bf(f.x);
    unsigned hi = ((unsigned)f2bf(f.w) << 16) | f2bf(f.z);
    ((uint2*)h_bf)[i] = make_uint2(lo, hi);
  }
  if (i < N_EDGES) atomicAdd(&count[dst[i]], 1);
}

// ---------------- scan of per-node counts (3 dispatches) ----------------

__global__ __launch_bounds__(256) void scan_part1(const int4* __restrict__ count4,
                                                  int* __restrict__ blocksum) {
  __shared__ int wsum[4];
  int b = blockIdx.x, t = threadIdx.x;
  int lane = t & 63, wid = t >> 6;
  int4 v = count4[b * 256 + t];
  int s = v.x + v.y + v.z + v.w;
#pragma unroll
  for (int off = 32; off >= 1; off >>= 1) s += __shfl_xor(s, off, 64);
  if (lane == 0) wsum[wid] = s;
  __syncthreads();
  if (t == 0) blocksum[b] = wsum[0] + wsum[1] + wsum[2] + wsum[3];
}

// wave 0: scan 49 block sums; all 1024 threads: convert W to bf16.
__global__ __launch_bounds__(1024) void scan2_convw(const int* __restrict__ blocksum,
                                                    int* __restrict__ blockoff,
                                                    const float4* __restrict__ Wm4,
                                                    ushort4* __restrict__ W4) {
  int t = threadIdx.x;
  if (t < 64) {
    int v = (t < SCAN_BLOCKS) ? blocksum[t] : 0;
    int incl = v;
#pragma unroll
    for (int off = 1; off < 64; off <<= 1) {
      int y = __shfl_up(incl, off, 64);
      if (t >= off) incl += y;
    }
    if (t < SCAN_BLOCKS) blockoff[t] = incl - v;
  }
  for (int i = t; i < D * D / 4; i += 1024) {
    float4 f = Wm4[i];
    ushort4 o;
    o.x = f2bf(f.x); o.y = f2bf(f.y); o.z = f2bf(f.z); o.w = f2bf(f.w);
    W4[i] = o;
  }
}

// row_start (padded; flat past N_NODES) + bucket cursors gcursor[b]=row_start[b*128]
__global__ __launch_bounds__(256) void scan_part3(const int4* __restrict__ count4,
                                                  const int* __restrict__ blockoff,
                                                  int4* __restrict__ row4,
                                                  int* __restrict__ gcursor) {
  __shared__ int wsum[4];
  int b = blockIdx.x, t = threadIdx.x;
  int lane = t & 63, wid = t >> 6;
  int4 v = count4[b * 256 + t];
  int s = v.x + v.y + v.z + v.w;
  int incl = s;
#pragma unroll
  for (int off = 1; off < 64; off <<= 1) {
    int y = __shfl_up(incl, off, 64);
    if (lane >= off) incl += y;
  }
  if (lane == 63) wsum[wid] = incl;
  __syncthreads();
  int woff = 0;
#pragma unroll
  for (int i = 0; i < 4; ++i) woff += (i < wid) ? wsum[i] : 0;
  int excl = incl - s + woff + blockoff[b];
  int4 p;
  p.x = excl;
  p.y = p.x + v.x;
  p.z = p.y + v.y;
  p.w = p.z + v.z;
  row4[b * 256 + t] = p;
  int node = b * 1024 + t * 4;
  if ((node & 127) == 0) gcursor[node >> 7] = p.x;
}

// ---------------- phase 1: LDS-staged partition by 128-node bucket -----------
// packed record: [src:16 | node_local:7 | w_q9:9]; lands inside its bucket's
// final CSR range (gcursor pre-initialized to bucket starts).
__global__ __launch_bounds__(256) void partition_kernel(const int* __restrict__ src,
                                                        const int* __restrict__ dst,
                                                        const float* __restrict__ w,
                                                        int* __restrict__ gcursor,
                                                        unsigned* __restrict__ csr4) {
  __shared__ int lhist[NBUCKET];
  __shared__ int lstart[NBUCKET];
  __shared__ int lcur[NBUCKET];
  __shared__ int gbase[NBUCKET];
  __shared__ unsigned staged_v[PCHUNK];
  __shared__ unsigned short staged_b[PCHUNK];
  int t = threadIdx.x;
  int e0 = blockIdx.x * PCHUNK;
  int nch = N_EDGES - e0; if (nch > PCHUNK) nch = PCHUNK;

  for (int i = t; i < NBUCKET; i += 256) lhist[i] = 0;
  __syncthreads();

  unsigned rec[PCHUNK / 256];
  int rbkt[PCHUNK / 256];
#pragma unroll
  for (int k = 0; k < PCHUNK / 256; ++k) {
    int idx = t + k * 256;
    if (idx < nch) {
      int e = e0 + idx;
      int s = src[e];
      int d_ = dst[e];
      unsigned q = (unsigned)__float2uint_rn(w[e] * 511.f);
      rbkt[k] = d_ >> 7;
      rec[k] = ((unsigned)s << 16) | ((unsigned)(d_ & 127) << 9) | q;
      atomicAdd(&lhist[rbkt[k]], 1);
    } else {
      rbkt[k] = -1;
      rec[k] = 0;
    }
  }
  __syncthreads();

  if (t < 64) {  // exclusive scan lhist -> lstart
    int carry = 0;
    for (int base = 0; base < NBUCKET; base += 64) {
      int i = base + t;
      int v = (i < NBUCKET) ? lhist[i] : 0;
      int incl = v;
#pragma unroll
      for (int off = 1; off < 64; off <<= 1) {
        int y = __shfl_up(incl, off, 64);
        if (t >= off) incl += y;
      }
      if (i < NBUCKET) lstart[i] = incl - v + carry;
      carry += __shfl(incl, 63, 64);
    }
  }
  __syncthreads();

  for (int i = t; i < NBUCKET; i += 256) {
    gbase[i] = (lhist[i] > 0) ? atomicAdd(&gcursor[i], lhist[i]) : 0;
    lcur[i] = lstart[i];
  }
  __syncthreads();

#pragma unroll
  for (int k = 0; k < PCHUNK / 256; ++k) {
    if (rbkt[k] >= 0) {
      int lp = atomicAdd(&lcur[rbkt[k]], 1);
      staged_v[lp] = rec[k];
      staged_b[lp] = (unsigned short)rbkt[k];
    }
  }
  __syncthreads();

  for (int i = t; i < nch; i += 256) {
    int bkt = staged_b[i];
    csr4[gbase[bkt] + (i - lstart[bkt])] = staged_v[i];
  }
}

// ---------------- phase 2: place records at exact CSR slot (8KB window) ------
__global__ __launch_bounds__(256) void scatter2_kernel(const unsigned* __restrict__ csr4,
                                                       const int* __restrict__ row_start,
                                                       unsigned* __restrict__ csr_ew) {
  __shared__ int lcur[128];
  int b = blockIdx.x, t = threadIdx.x;
  if (t < 128) lcur[t] = row_start[b * 128 + t];
  __syncthreads();
  int beg = row_start[b * 128];
  int end = ((b + 1) * 128 <= N_PAD - 1) ? row_start[(b + 1) * 128] : N_EDGES;
  for (int i = beg + t; i < end; i += 256) {
    unsigned v = csr4[i];
    int nl = (v >> 9) & 127;
    int pos = atomicAdd(&lcur[nl], 1);
    csr_ew[pos] = v;
  }
}

// ---------------- aggregate: mean of h[src]*w by dst, then tanh ----------------
// One 64-lane wave per node; lane owns channels {2*lane, 2*lane+1} packed in a uint.
__global__ __launch_bounds__(256) void aggregate_kernel(const unsigned* __restrict__ h_bf,
                                                        const unsigned* __restrict__ csr_ew,
                                                        const int* __restrict__ row_start,
                                                        float* __restrict__ hact) {
  int node = blockIdx.x * 4 + (threadIdx.x >> 6);
  int lane = threadIdx.x & 63;
  if (node >= N_NODES) return;
  int beg = row_start[node], end = row_start[node + 1];
  const float WS = 1.0f / 511.0f;
  float a0 = 0.f, a1 = 0.f;
  int e = beg;
  for (; e + 4 <= end; e += 4) {
    unsigned p0 = csr_ew[e],   p1 = csr_ew[e+1], p2 = csr_ew[e+2], p3 = csr_ew[e+3];
    unsigned v0 = h_bf[(p0 >> 16) * 64 + lane];
    unsigned v1 = h_bf[(p1 >> 16) * 64 + lane];
    unsigned v2 = h_bf[(p2 >> 16) * 64 + lane];
    unsigned v3 = h_bf[(p3 >> 16) * 64 + lane];
    float w0 = (float)(p0 & 0x1FFu) * WS;
    float w1 = (float)(p1 & 0x1FFu) * WS;
    float w2 = (float)(p2 & 0x1FFu) * WS;
    float w3 = (float)(p3 & 0x1FFu) * WS;
    a0 = fmaf(__uint_as_float(v0 << 16), w0, a0);
    a1 = fmaf(__uint_as_float(v0 & 0xFFFF0000u), w0, a1);
    a0 = fmaf(__uint_as_float(v1 << 16), w1, a0);
    a1 = fmaf(__uint_as_float(v1 & 0xFFFF0000u), w1, a1);
    a0 = fmaf(__uint_as_float(v2 << 16), w2, a0);
    a1 = fmaf(__uint_as_float(v2 & 0xFFFF0000u), w2, a1);
    a0 = fmaf(__uint_as_float(v3 << 16), w3, a0);
    a1 = fmaf(__uint_as_float(v3 & 0xFFFF0000u), w3, a1);
  }
  for (; e < end; ++e) {
    unsigned p = csr_ew[e];
    unsigned v = h_bf[(p >> 16) * 64 + lane];
    float we = (float)(p & 0x1FFu) * WS;
    a0 = fmaf(__uint_as_float(v << 16), we, a0);
    a1 = fmaf(__uint_as_float(v & 0xFFFF0000u), we, a1);
  }
  int deg = end - beg;
  float inv = (deg > 0) ? 1.f / (float)deg : 0.f;
  float2 r;
  r.x = tanhf(a0 * inv);
  r.y = tanhf(a1 * inv);
  ((float2*)hact)[node * 64 + lane] = r;
}

// ---------------- out = tanh-act @ W^T + b via MFMA bf16, in place on d_out ----
__global__ __launch_bounds__(256) void gemm_kernel(const float* __restrict__ hact,
                                                   const unsigned short* __restrict__ W_bf,
                                                   const float* __restrict__ bias,
                                                   float* __restrict__ out) {
  int lane = threadIdx.x & 63;
  int wid  = threadIdx.x >> 6;
  int n_base = blockIdx.x * 64 + wid * 16;
  int m  = lane & 15;
  int kg = lane >> 4;
  int n = n_base + m;
  int n_c = (n < N_NODES) ? n : (N_NODES - 1);

  bf16x8 afrag[4];
  const float* arow = hact + (size_t)n_c * D;
#pragma unroll
  for (int kc = 0; kc < 4; ++kc) {
    int k0 = kc * 32 + kg * 8;
    float4 lo = *(const float4*)(arow + k0);
    float4 hi = *(const float4*)(arow + k0 + 4);
    bf16x8 a;
    a[0] = (short)f2bf(lo.x); a[1] = (short)f2bf(lo.y);
    a[2] = (short)f2bf(lo.z); a[3] = (short)f2bf(lo.w);
    a[4] = (short)f2bf(hi.x); a[5] = (short)f2bf(hi.y);
    a[6] = (short)f2bf(hi.z); a[7] = (short)f2bf(hi.w);
    afrag[kc] = a;
  }

#pragma unroll
  for (int jt = 0; jt < 8; ++jt) {
    int j = jt * 16 + m;
    const unsigned short* wrow = W_bf + j * D;
    f32x4 acc = {0.f, 0.f, 0.f, 0.f};
#pragma unroll
    for (int kc = 0; kc < 4; ++kc) {
      bf16x8 bb = *(const bf16x8*)(wrow + kc * 32 + kg * 8);
      acc = __builtin_amdgcn_mfma_f32_16x16x32_bf16(afrag[kc], bb, acc, 0, 0, 0);
    }
    float bj = bias[j];
#pragma unroll
    for (int rr = 0; rr < 4; ++rr) {
      int nn = n_base + kg * 4 + rr;
      if (nn < N_NODES) out[(size_t)nn * D + j] = acc[rr] + bj;
    }
  }
}

extern "C" void kernel_launch(void* const* d_in, const int* in_sizes, int n_in,
                              void* d_out, int out_size, void* d_ws, size_t ws_size,
                              hipStream_t stream) {
  const float* h    = (const float*)d_in[0];
  const float* w    = (const float*)d_in[1];
  const int*   src  = (const int*)d_in[2];
  const int*   dst  = (const int*)d_in[3];
  const float* Wm   = (const float*)d_in[4];
  const float* bias = (const float*)d_in[5];
  float* out = (float*)d_out;

  // ws layout (16B-aligned), total 19,636,288 B (< known 19.83MB floor):
  //   count:     [0,        200704)
  //   row_start: [200704,   401408)    (padded; row_start[N] valid, flat past N)
  //   blocksum:  [401408,   401664)
  //   blockoff:  [401664,   401920)
  //   gcursor:   [401920,   403520)    (392 bucket cursors = CSR bucket starts)
  //   W_bf:      [403520,   436288)
  //   h_bf:      [436288,   13236288)  (12.8 MB)
  //   csr4:      [13236288, 16436288)  (bucket-grouped packed records)
  //   csr_ew:    [16436288, 19636288)  (final CSR order)
  char* ws = (char*)d_ws;
  int*            count     = (int*)(ws);
  int*            row_start = (int*)(ws + 200704);
  int*            blocksum  = (int*)(ws + 401408);
  int*            blockoff  = (int*)(ws + 401664);
  int*            gcursor   = (int*)(ws + 401920);
  unsigned short* W_bf      = (unsigned short*)(ws + 403520);
  unsigned*       h_bf      = (unsigned*)(ws + 436288);
  unsigned*       csr4      = (unsigned*)(ws + 13236288);
  unsigned*       csr_ew    = (unsigned*)(ws + 16436288);

  hipMemsetAsync(count, 0, N_PAD * sizeof(int), stream);
  prep_kernel<<<(N_NODES * D / 4 + 255) / 256, 256, 0, stream>>>(h, h_bf, dst, count);
  scan_part1<<<SCAN_BLOCKS, 256, 0, stream>>>((const int4*)count, blocksum);
  scan2_convw<<<1, 1024, 0, stream>>>(blocksum, blockoff, (const float4*)Wm, (ushort4*)W_bf);
  scan_part3<<<SCAN_BLOCKS, 256, 0, stream>>>((const int4*)count, blockoff,
                                              (int4*)row_start, gcursor);
  partition_kernel<<<NPBLK, 256, 0, stream>>>(src, dst, w, gcursor, csr4);
  scatter2_kernel<<<391, 256, 0, stream>>>(csr4, row_start, csr_ew);
  aggregate_kernel<<<(N_NODES + 3) / 4, 256, 0, stream>>>(h_bf, csr_ew, row_start, out);
  gemm_kernel<<<(N_NODES + 63) / 64, 256, 0, stream>>>(out, W_bf, bias, out);
}